// Round 1
// baseline (22500.716 us; speedup 1.0000x reference)
//
#include <hip/hip_runtime.h>

typedef _Float16 f16;
typedef _Float16 f16x4 __attribute__((ext_vector_type(4)));
typedef _Float16 f16x8 __attribute__((ext_vector_type(8)));
typedef float f32x4 __attribute__((ext_vector_type(4)));
typedef unsigned long long u64;

#define NB 32      // batch
#define NT 2048    // timesteps
#define ND 512     // input dim
#define NH 512     // hidden dim
#define NG 2048    // 4*NH gates
#define NWG 16     // workgroups (each owns 32 h-cols)
#define WGC 32     // h-cols per WG

__device__ __forceinline__ float sigf(float x)  { return 1.0f / (1.0f + __expf(-x)); }
__device__ __forceinline__ float tanhf_(float x){ return 2.0f / (1.0f + __expf(-2.0f * x)) - 1.0f; }

// ---- init: reset barrier counter, stage h(0)=h_prev as fp16 into hg[0] ----
__global__ void lstm_init(const float* __restrict__ hprev,
                          u64* __restrict__ hg, unsigned int* __restrict__ cnt) {
  const int tid = threadIdx.x;
  if (tid == 0) *cnt = 0u;
  // hg[0] : 32x512 fp16 = 4096 u64 words
  for (int i = 0; i < 16; ++i) {
    const int f = tid + 256 * i;
    const int m = f >> 7, c0 = (f & 127) << 2;
    const float* s = hprev + m * NH + c0;
    union { u64 u; f16 h[4]; } pk;
    pk.h[0] = (f16)s[0]; pk.h[1] = (f16)s[1]; pk.h[2] = (f16)s[2]; pk.h[3] = (f16)s[3];
    hg[f] = pk.u;
  }
}

// ---- persistent recurrent kernel: 16 WGs x 256 threads ----
__global__ void __launch_bounds__(256, 1)
lstm_rec(const float* __restrict__ X,     // [B][T][D]
         const float* __restrict__ Whh,   // [4H][H]
         const float* __restrict__ Wih,   // [4H][D]
         const float* __restrict__ bias,  // [4H]
         float* __restrict__ out,         // [B][H]
         u64* __restrict__ hg,            // [2][32][512] fp16 as u64 words
         unsigned int* __restrict__ cnt) {
  __shared__ f16  h_lds[32 * 520];   // h(t) fp16, padded stride 520
  __shared__ f16  x_lds[32 * 520];   // x(t) fp16, padded stride 520
  __shared__ float g_lds[32 * 128];  // gate pre-activations
  __shared__ float bias_lds[128];

  const int tid  = threadIdx.x;
  const int wgid = blockIdx.x;
  const int wv   = tid >> 6;        // wave 0..3 -> gate type q
  const int lane = tid & 63;
  const int l15  = lane & 15;
  const int ko   = (lane >> 4) * 8; // k offset within a 32-wide k-tile

  if (tid < 128)
    bias_lds[tid] = bias[(tid >> 5) * NH + wgid * WGC + (tid & 31)];

  // --- load W fragments into VGPRs: wf[nt2][kt]; kt<16 -> Whh, else Wih ---
  f16x8 wf[2][32];
#pragma unroll
  for (int nt2 = 0; nt2 < 2; ++nt2) {
    const int grow = wv * NH + wgid * WGC + nt2 * 16 + l15;  // global gate row
#pragma unroll
    for (int kt = 0; kt < 32; ++kt) {
      const float* src = (kt < 16) ? (Whh + (size_t)grow * NH + kt * 32 + ko)
                                   : (Wih + (size_t)grow * ND + (kt - 16) * 32 + ko);
      f32x4 u0 = *(const f32x4*)(src);
      f32x4 u1 = *(const f32x4*)(src + 4);
      f16x8 w;
      w[0] = (f16)u0[0]; w[1] = (f16)u0[1]; w[2] = (f16)u0[2]; w[3] = (f16)u0[3];
      w[4] = (f16)u1[0]; w[5] = (f16)u1[1]; w[6] = (f16)u1[2]; w[7] = (f16)u1[3];
      wf[nt2][kt] = w;
    }
  }

  // elementwise ownership: (em, ej0..ej0+3)
  const int em  = tid >> 3;
  const int ej0 = (tid & 7) * 4;
  // x staging ownership
  const int sm  = tid >> 3;
  const int sd0 = (tid & 7) * 64;

  // --- stage x(0) into x_lds ---
  {
    const float* xs = X + ((size_t)sm * NT + 0) * ND + sd0;
#pragma unroll
    for (int i = 0; i < 16; ++i) {
      f32x4 v = *(const f32x4*)(xs + 4 * i);
      f16x4 hvv; hvv[0]=(f16)v[0]; hvv[1]=(f16)v[1]; hvv[2]=(f16)v[2]; hvv[3]=(f16)v[3];
      *(f16x4*)&x_lds[sm * 520 + sd0 + 4 * i] = hvv;
    }
  }

  float c0 = 0.f, c1 = 0.f, c2 = 0.f, c3 = 0.f;
  __syncthreads();

  for (int t = 0; t < NT; ++t) {
    // --- prefetch x(t+1) (issued before the spin so HBM latency hides) ---
    const int tn = (t < NT - 1) ? t + 1 : NT - 1;
    const float* xs = X + ((size_t)sm * NT + tn) * ND + sd0;
    f32x4 xr[16];
#pragma unroll
    for (int i = 0; i < 16; ++i) xr[i] = *(const f32x4*)(xs + 4 * i);

    // --- barrier: wait for h(t) from all WGs ---
    if (t > 0) {
      if (tid == 0) {
        const unsigned int tgt = (unsigned int)(NWG * t);
        while (__hip_atomic_load(cnt, __ATOMIC_ACQUIRE, __HIP_MEMORY_SCOPE_AGENT) < tgt) {}
      }
      __syncthreads();
    }

    // --- gather h(t) (device-scope atomic loads -> LDS) ---
    {
      u64* src = hg + (size_t)(t & 1) * 4096;
#pragma unroll
      for (int i = 0; i < 16; ++i) {
        const int f = tid + 256 * i;
        u64 v = __hip_atomic_load(src + f, __ATOMIC_RELAXED, __HIP_MEMORY_SCOPE_AGENT);
        *(u64*)&h_lds[(f >> 7) * 520 + (f & 127) * 4] = v;
      }
    }
    __syncthreads();

    // --- MFMA: gates[32 x 128] = [h | x] . [Whh | Wih]^T slice ---
    f32x4 a00 = {0,0,0,0}, a01 = {0,0,0,0}, a10 = {0,0,0,0}, a11 = {0,0,0,0};
#pragma unroll
    for (int kt = 0; kt < 32; ++kt) {
      const f16* ap = (kt < 16) ? &h_lds[l15 * 520 + kt * 32 + ko]
                                : &x_lds[l15 * 520 + (kt - 16) * 32 + ko];
      f16x8 af0 = *(const f16x8*)ap;
      f16x8 af1 = *(const f16x8*)(ap + 16 * 520);
      a00 = __builtin_amdgcn_mfma_f32_16x16x32_f16(af0, wf[0][kt], a00, 0, 0, 0);
      a01 = __builtin_amdgcn_mfma_f32_16x16x32_f16(af0, wf[1][kt], a01, 0, 0, 0);
      a10 = __builtin_amdgcn_mfma_f32_16x16x32_f16(af1, wf[0][kt], a10, 0, 0, 0);
      a11 = __builtin_amdgcn_mfma_f32_16x16x32_f16(af1, wf[1][kt], a11, 0, 0, 0);
    }

    // --- acc -> g_lds (D frag: col=lane&15, row=(lane>>4)*4+reg) ---
    {
      const int col0 = wv * 32 + l15;
      const int mrow = (lane >> 4) * 4;
#pragma unroll
      for (int r = 0; r < 4; ++r) {
        g_lds[(mrow + r) * 128 + col0]            = a00[r];
        g_lds[(mrow + r) * 128 + col0 + 16]       = a01[r];
        g_lds[(16 + mrow + r) * 128 + col0]       = a10[r];
        g_lds[(16 + mrow + r) * 128 + col0 + 16]  = a11[r];
      }
    }
    __syncthreads();

    // --- elementwise LSTM cell for (em, ej0..ej0+3) ---
    {
      const float* gr = g_lds + em * 128;
      f32x4 vi = *(const f32x4*)(gr + ej0)      ;
      f32x4 vf = *(const f32x4*)(gr + 32 + ej0) ;
      f32x4 vg = *(const f32x4*)(gr + 64 + ej0) ;
      f32x4 vo = *(const f32x4*)(gr + 96 + ej0) ;
      f32x4 bi = *(const f32x4*)(bias_lds + ej0);
      f32x4 bf = *(const f32x4*)(bias_lds + 32 + ej0);
      f32x4 bg = *(const f32x4*)(bias_lds + 64 + ej0);
      f32x4 bo = *(const f32x4*)(bias_lds + 96 + ej0);

      float hv[4];
#pragma unroll
      for (int p = 0; p < 4; ++p) {
        float ig = sigf(vi[p] + bi[p]);
        float fg = sigf(vf[p] + bf[p]);
        float gg = tanhf_(vg[p] + bg[p]);
        float og = sigf(vo[p] + bo[p]);
        float& cc = (p == 0 ? c0 : p == 1 ? c1 : p == 2 ? c2 : c3);
        cc = fg * cc + ig * gg;
        hv[p] = og * tanhf_(cc);
      }
      union { u64 u; f16 h[4]; } pk;
      pk.h[0] = (f16)hv[0]; pk.h[1] = (f16)hv[1]; pk.h[2] = (f16)hv[2]; pk.h[3] = (f16)hv[3];
      __hip_atomic_store(hg + (size_t)((t + 1) & 1) * 4096 + em * 128 + wgid * 8 + (ej0 >> 2),
                         pk.u, __ATOMIC_RELAXED, __HIP_MEMORY_SCOPE_AGENT);
      if (t == NT - 1) {
        f32x4 o4; o4[0] = hv[0]; o4[1] = hv[1]; o4[2] = hv[2]; o4[3] = hv[3];
        *(f32x4*)&out[(size_t)em * NH + wgid * WGC + ej0] = o4;
      }
    }

    // --- store prefetched x(t+1) into x_lds (all waves are past MFMA reads) ---
#pragma unroll
    for (int i = 0; i < 16; ++i) {
      f16x4 hvv; hvv[0]=(f16)xr[i][0]; hvv[1]=(f16)xr[i][1]; hvv[2]=(f16)xr[i][2]; hvv[3]=(f16)xr[i][3];
      *(f16x4*)&x_lds[sm * 520 + sd0 + 4 * i] = hvv;
    }

    // --- publish h(t+1) ---
    __threadfence();
    __syncthreads();   // drains vmcnt: all atomic stores complete
    if (tid == 0)
      __hip_atomic_fetch_add(cnt, 1u, __ATOMIC_RELEASE, __HIP_MEMORY_SCOPE_AGENT);
  }
}

extern "C" void kernel_launch(void* const* d_in, const int* in_sizes, int n_in,
                              void* d_out, int out_size, void* d_ws, size_t ws_size,
                              hipStream_t stream) {
  const float* X     = (const float*)d_in[0];  // [32][2048][512]
  const float* hprev = (const float*)d_in[1];  // [32][512]
  const float* Wih   = (const float*)d_in[2];  // [2048][512]
  const float* Whh   = (const float*)d_in[3];  // [2048][512]
  const float* bias  = (const float*)d_in[4];  // [2048]
  float* out = (float*)d_out;

  u64* hg = (u64*)d_ws;                                   // 2*4096*8 = 64 KB
  unsigned int* cnt = (unsigned int*)((char*)d_ws + 2 * 4096 * 8);

  hipLaunchKernelGGL(lstm_init, dim3(1), dim3(256), 0, stream, hprev, hg, cnt);
  hipLaunchKernelGGL(lstm_rec, dim3(NWG), dim3(256), 0, stream,
                     X, Whh, Wih, bias, out, hg, cnt);
}

// Round 2
// 13484.451 us; speedup vs baseline: 1.6686x; 1.6686x over previous
//
#include <hip/hip_runtime.h>

typedef _Float16 f16;
typedef _Float16 f16x4 __attribute__((ext_vector_type(4)));
typedef _Float16 f16x8 __attribute__((ext_vector_type(8)));
typedef float f32x4 __attribute__((ext_vector_type(4)));
typedef unsigned long long u64;

#define NB 32      // batch
#define NT 2048    // timesteps
#define ND 512     // input dim
#define NH 512     // hidden dim
#define NWG 16     // workgroups (each owns 32 h-cols)
#define WGC 32     // h-cols per WG

__device__ __forceinline__ float sigf(float x)  { return 1.0f / (1.0f + __expf(-x)); }
__device__ __forceinline__ float tanhf_(float x){ return 2.0f / (1.0f + __expf(-2.0f * x)) - 1.0f; }

// ---- init: reset barrier counter, stage h(0)=h_prev as fp16 into hg[0] ----
__global__ void lstm_init(const float* __restrict__ hprev,
                          u64* __restrict__ hg, unsigned int* __restrict__ cnt) {
  const int tid = threadIdx.x;
  if (tid == 0) *cnt = 0u;
  // hg[0] : 32x512 fp16 = 4096 u64 words
  for (int i = 0; i < 16; ++i) {
    const int f = tid + 256 * i;
    const int m = f >> 7, c0 = (f & 127) << 2;
    const float* s = hprev + m * NH + c0;
    union { u64 u; f16 h[4]; } pk;
    pk.h[0] = (f16)s[0]; pk.h[1] = (f16)s[1]; pk.h[2] = (f16)s[2]; pk.h[3] = (f16)s[3];
    hg[f] = pk.u;
  }
}

// ---- persistent recurrent kernel: 16 WGs x 256 threads ----
__global__ void __launch_bounds__(256, 1)
lstm_rec(const float* __restrict__ X,     // [B][T][D]
         const float* __restrict__ Whh,   // [4H][H]
         const float* __restrict__ Wih,   // [4H][D]
         const float* __restrict__ bias,  // [4H]
         float* __restrict__ out,         // [B][H]
         u64* __restrict__ hg,            // [2][32][512] fp16 as u64 words
         unsigned int* __restrict__ cnt) {
  __shared__ f16  h_lds[32 * 520];   // h(t) fp16, padded stride 520
  __shared__ f16  x_lds[32 * 520];   // x(t) fp16, padded stride 520
  __shared__ float g_lds[32 * 128];  // gate pre-activations
  __shared__ float bias_lds[128];

  const int tid  = threadIdx.x;
  const int wgid = blockIdx.x;
  const int wv   = tid >> 6;        // wave 0..3 -> gate type q
  const int lane = tid & 63;
  const int l15  = lane & 15;
  const int ko   = (lane >> 4) * 8; // k offset within a 32-wide k-tile

  if (tid < 128)
    bias_lds[tid] = bias[(tid >> 5) * NH + wgid * WGC + (tid & 31)];

  // --- load W fragments into VGPRs: wf[nt2][kt]; kt<16 -> Whh, else Wih ---
  f16x8 wf[2][32];
#pragma unroll
  for (int nt2 = 0; nt2 < 2; ++nt2) {
    const int grow = wv * NH + wgid * WGC + nt2 * 16 + l15;  // global gate row
#pragma unroll
    for (int kt = 0; kt < 32; ++kt) {
      const float* src = (kt < 16) ? (Whh + (size_t)grow * NH + kt * 32 + ko)
                                   : (Wih + (size_t)grow * ND + (kt - 16) * 32 + ko);
      f32x4 u0 = *(const f32x4*)(src);
      f32x4 u1 = *(const f32x4*)(src + 4);
      f16x8 w;
      w[0] = (f16)u0[0]; w[1] = (f16)u0[1]; w[2] = (f16)u0[2]; w[3] = (f16)u0[3];
      w[4] = (f16)u1[0]; w[5] = (f16)u1[1]; w[6] = (f16)u1[2]; w[7] = (f16)u1[3];
      wf[nt2][kt] = w;
    }
  }

  // elementwise ownership: (em, ej0..ej0+3)
  const int em  = tid >> 3;
  const int ej0 = (tid & 7) * 4;
  // x staging ownership
  const int sm  = tid >> 3;
  const int sd0 = (tid & 7) * 64;

  // --- stage x(0) into x_lds ---
  {
    const float* xs = X + ((size_t)sm * NT + 0) * ND + sd0;
#pragma unroll
    for (int i = 0; i < 16; ++i) {
      f32x4 v = *(const f32x4*)(xs + 4 * i);
      f16x4 hvv; hvv[0]=(f16)v[0]; hvv[1]=(f16)v[1]; hvv[2]=(f16)v[2]; hvv[3]=(f16)v[3];
      *(f16x4*)&x_lds[sm * 520 + sd0 + 4 * i] = hvv;
    }
  }

  float c0 = 0.f, c1 = 0.f, c2 = 0.f, c3 = 0.f;
  __syncthreads();

  for (int t = 0; t < NT; ++t) {
    // --- prefetch x(t+1) (issued before the spin so HBM latency hides) ---
    const int tn = (t < NT - 1) ? t + 1 : NT - 1;
    const float* xs = X + ((size_t)sm * NT + tn) * ND + sd0;
    f32x4 xr[16];
#pragma unroll
    for (int i = 0; i < 16; ++i) xr[i] = *(const f32x4*)(xs + 4 * i);

    // --- barrier: wait for h(t) from all WGs (RELAXED poll: no cache-maint ops) ---
    if (t > 0) {
      if (tid == 0) {
        const unsigned int tgt = (unsigned int)(NWG * t);
        while (__hip_atomic_load(cnt, __ATOMIC_RELAXED, __HIP_MEMORY_SCOPE_AGENT) < tgt) {}
      }
      __syncthreads();   // also a compiler barrier: gather can't hoist above poll
    }

    // --- gather h(t): issue all 16 LLC loads, then write LDS ---
    {
      u64* src = hg + (size_t)(t & 1) * 4096;
      u64 hv16[16];
#pragma unroll
      for (int i = 0; i < 16; ++i)
        hv16[i] = __hip_atomic_load(src + tid + 256 * i, __ATOMIC_RELAXED, __HIP_MEMORY_SCOPE_AGENT);
#pragma unroll
      for (int i = 0; i < 16; ++i) {
        const int f = tid + 256 * i;
        *(u64*)&h_lds[(f >> 7) * 520 + (f & 127) * 4] = hv16[i];
      }
    }
    __syncthreads();

    // --- MFMA: gates[32 x 128] = [h | x] . [Whh | Wih]^T slice ---
    f32x4 a00 = {0,0,0,0}, a01 = {0,0,0,0}, a10 = {0,0,0,0}, a11 = {0,0,0,0};
#pragma unroll
    for (int kt = 0; kt < 32; ++kt) {
      const f16* ap = (kt < 16) ? &h_lds[l15 * 520 + kt * 32 + ko]
                                : &x_lds[l15 * 520 + (kt - 16) * 32 + ko];
      f16x8 af0 = *(const f16x8*)ap;
      f16x8 af1 = *(const f16x8*)(ap + 16 * 520);
      a00 = __builtin_amdgcn_mfma_f32_16x16x32_f16(af0, wf[0][kt], a00, 0, 0, 0);
      a01 = __builtin_amdgcn_mfma_f32_16x16x32_f16(af0, wf[1][kt], a01, 0, 0, 0);
      a10 = __builtin_amdgcn_mfma_f32_16x16x32_f16(af1, wf[0][kt], a10, 0, 0, 0);
      a11 = __builtin_amdgcn_mfma_f32_16x16x32_f16(af1, wf[1][kt], a11, 0, 0, 0);
    }

    // --- acc -> g_lds (D frag: col=lane&15, row=(lane>>4)*4+reg) ---
    {
      const int col0 = wv * 32 + l15;
      const int mrow = (lane >> 4) * 4;
#pragma unroll
      for (int r = 0; r < 4; ++r) {
        g_lds[(mrow + r) * 128 + col0]            = a00[r];
        g_lds[(mrow + r) * 128 + col0 + 16]       = a01[r];
        g_lds[(16 + mrow + r) * 128 + col0]       = a10[r];
        g_lds[(16 + mrow + r) * 128 + col0 + 16]  = a11[r];
      }
    }
    __syncthreads();

    // --- elementwise LSTM cell for (em, ej0..ej0+3) ---
    {
      const float* gr = g_lds + em * 128;
      f32x4 vi = *(const f32x4*)(gr + ej0)      ;
      f32x4 vf = *(const f32x4*)(gr + 32 + ej0) ;
      f32x4 vg = *(const f32x4*)(gr + 64 + ej0) ;
      f32x4 vo = *(const f32x4*)(gr + 96 + ej0) ;
      f32x4 bi = *(const f32x4*)(bias_lds + ej0);
      f32x4 bf = *(const f32x4*)(bias_lds + 32 + ej0);
      f32x4 bg = *(const f32x4*)(bias_lds + 64 + ej0);
      f32x4 bo = *(const f32x4*)(bias_lds + 96 + ej0);

      float hv[4];
#pragma unroll
      for (int p = 0; p < 4; ++p) {
        float ig = sigf(vi[p] + bi[p]);
        float fg = sigf(vf[p] + bf[p]);
        float gg = tanhf_(vg[p] + bg[p]);
        float og = sigf(vo[p] + bo[p]);
        float& cc = (p == 0 ? c0 : p == 1 ? c1 : p == 2 ? c2 : c3);
        cc = fg * cc + ig * gg;
        hv[p] = og * tanhf_(cc);
      }
      union { u64 u; f16 h[4]; } pk;
      pk.h[0] = (f16)hv[0]; pk.h[1] = (f16)hv[1]; pk.h[2] = (f16)hv[2]; pk.h[3] = (f16)hv[3];
      __hip_atomic_store(hg + (size_t)((t + 1) & 1) * 4096 + em * 128 + wgid * 8 + (ej0 >> 2),
                         pk.u, __ATOMIC_RELAXED, __HIP_MEMORY_SCOPE_AGENT);
      if (t == NT - 1) {
        f32x4 o4; o4[0] = hv[0]; o4[1] = hv[1]; o4[2] = hv[2]; o4[3] = hv[3];
        *(f32x4*)&out[(size_t)em * NH + wgid * WGC + ej0] = o4;
      }
    }

    // --- store prefetched x(t+1) into x_lds (all waves are past MFMA reads) ---
#pragma unroll
    for (int i = 0; i < 16; ++i) {
      f16x4 hvv; hvv[0]=(f16)xr[i][0]; hvv[1]=(f16)xr[i][1]; hvv[2]=(f16)xr[i][2]; hvv[3]=(f16)xr[i][3];
      *(f16x4*)&x_lds[sm * 520 + sd0 + 4 * i] = hvv;
    }

    // --- publish h(t+1): ack h-stores at LLC, then bump counter (no L2 wb/inv) ---
    asm volatile("s_waitcnt vmcnt(0)" ::: "memory");
    __syncthreads();   // all threads' h-stores acked at the coherent point
    if (tid == 0)
      __hip_atomic_fetch_add(cnt, 1u, __ATOMIC_RELAXED, __HIP_MEMORY_SCOPE_AGENT);
  }
}

extern "C" void kernel_launch(void* const* d_in, const int* in_sizes, int n_in,
                              void* d_out, int out_size, void* d_ws, size_t ws_size,
                              hipStream_t stream) {
  const float* X     = (const float*)d_in[0];  // [32][2048][512]
  const float* hprev = (const float*)d_in[1];  // [32][512]
  const float* Wih   = (const float*)d_in[2];  // [2048][512]
  const float* Whh   = (const float*)d_in[3];  // [2048][512]
  const float* bias  = (const float*)d_in[4];  // [2048]
  float* out = (float*)d_out;

  u64* hg = (u64*)d_ws;                                   // 2*4096*8 = 64 KB
  unsigned int* cnt = (unsigned int*)((char*)d_ws + 2 * 4096 * 8);

  hipLaunchKernelGGL(lstm_init, dim3(1), dim3(256), 0, stream, hprev, hg, cnt);
  hipLaunchKernelGGL(lstm_rec, dim3(NWG), dim3(256), 0, stream,
                     X, Whh, Wih, bias, out, hg, cnt);
}

// Round 3
// 12953.479 us; speedup vs baseline: 1.7370x; 1.0410x over previous
//
#include <hip/hip_runtime.h>

typedef _Float16 f16;
typedef _Float16 f16x4 __attribute__((ext_vector_type(4)));
typedef _Float16 f16x8 __attribute__((ext_vector_type(8)));
typedef float f32x4 __attribute__((ext_vector_type(4)));
typedef unsigned long long u64;

#define NB 32      // batch
#define NT 2048    // timesteps
#define ND 512     // input dim
#define NH 512     // hidden dim
#define NWG 16     // workgroups (each owns 32 h-cols)
#define WGC 32     // h-cols per WG
#define SENT 0xFFFFFFFFFFFFFFFFull   // 4x fp16 NaN — unreachable as real h data

// hg4: 4 rotating buffers [4][32*128] u64 words; word = m*128 + (hcol>>2)

__device__ __forceinline__ float sigf(float x)  { return 1.0f / (1.0f + __expf(-x)); }
__device__ __forceinline__ float tanhf_(float x){ return 2.0f / (1.0f + __expf(-2.0f * x)) - 1.0f; }

// ---- init: buffer0 = h_prev fp16-packed; buffers 1..3 = sentinel ----
__global__ void lstm_init(const float* __restrict__ hprev, u64* __restrict__ hg4) {
  const int g = blockIdx.x * 256 + threadIdx.x;   // 0..4095
  const int m = g >> 7, c0 = (g & 127) << 2;
  const float* s = hprev + m * NH + c0;
  union { u64 u; f16 h[4]; } pk;
  pk.h[0] = (f16)s[0]; pk.h[1] = (f16)s[1]; pk.h[2] = (f16)s[2]; pk.h[3] = (f16)s[3];
  hg4[g] = pk.u;
  hg4[4096 + g] = SENT;
  hg4[2 * 4096 + g] = SENT;
  hg4[3 * 4096 + g] = SENT;
}

// ---- persistent recurrent kernel: 16 WGs x 256 threads ----
__global__ void __launch_bounds__(256, 1)
lstm_rec(const float* __restrict__ X,     // [B][T][D]
         const float* __restrict__ Whh,   // [4H][H]
         const float* __restrict__ Wih,   // [4H][D]
         const float* __restrict__ bias,  // [4H]
         float* __restrict__ out,         // [B][H]
         u64* __restrict__ hg4) {         // [4][4096]
  __shared__ f16  h_lds[32 * 520];   // h(t) fp16, padded stride 520
  __shared__ f16  x_lds[32 * 520];   // x(t) fp16, padded stride 520
  __shared__ float g_lds[32 * 128];  // gate pre-activations
  __shared__ float bias_lds[128];

  const int tid  = threadIdx.x;
  const int wgid = blockIdx.x;
  const int wv   = tid >> 6;        // wave 0..3 -> gate type q
  const int lane = tid & 63;
  const int l15  = lane & 15;
  const int ko   = (lane >> 4) * 8; // k offset within a 32-wide k-tile

  if (tid < 128)
    bias_lds[tid] = bias[(tid >> 5) * NH + wgid * WGC + (tid & 31)];

  // --- load W fragments into VGPRs: wf[nt2][kt]; kt<16 -> Whh, else Wih ---
  f16x8 wf[2][32];
#pragma unroll
  for (int nt2 = 0; nt2 < 2; ++nt2) {
    const int grow = wv * NH + wgid * WGC + nt2 * 16 + l15;  // global gate row
#pragma unroll
    for (int kt = 0; kt < 32; ++kt) {
      const float* src = (kt < 16) ? (Whh + (size_t)grow * NH + kt * 32 + ko)
                                   : (Wih + (size_t)grow * ND + (kt - 16) * 32 + ko);
      f32x4 u0 = *(const f32x4*)(src);
      f32x4 u1 = *(const f32x4*)(src + 4);
      f16x8 w;
      w[0] = (f16)u0[0]; w[1] = (f16)u0[1]; w[2] = (f16)u0[2]; w[3] = (f16)u0[3];
      w[4] = (f16)u1[0]; w[5] = (f16)u1[1]; w[6] = (f16)u1[2]; w[7] = (f16)u1[3];
      wf[nt2][kt] = w;
    }
  }

  // elementwise ownership: (em, ej0..ej0+3); my hg word:
  const int em  = tid >> 3;
  const int ej0 = (tid & 7) * 4;
  const int myword = em * 128 + wgid * 8 + (tid & 7);
  // x staging ownership
  const int sm  = tid >> 3;
  const int sd0 = (tid & 7) * 64;

  // --- stage x(0) into x_lds ---
  {
    const float* xs = X + ((size_t)sm * NT + 0) * ND + sd0;
#pragma unroll
    for (int i = 0; i < 16; ++i) {
      f32x4 v = *(const f32x4*)(xs + 4 * i);
      f16x4 hvv; hvv[0]=(f16)v[0]; hvv[1]=(f16)v[1]; hvv[2]=(f16)v[2]; hvv[3]=(f16)v[3];
      *(f16x4*)&x_lds[sm * 520 + sd0 + 4 * i] = hvv;
    }
  }

  float c0 = 0.f, c1 = 0.f, c2 = 0.f, c3 = 0.f;
  __syncthreads();

  for (int t = 0; t < NT; ++t) {
    // --- (1) reset my word of buffer (t+2)&3 to sentinel (safe: all WGs are
    //     provably past step t-2's gather of this buffer) ---
    __hip_atomic_store(hg4 + (size_t)((t + 2) & 3) * 4096 + myword, SENT,
                       __ATOMIC_RELAXED, __HIP_MEMORY_SCOPE_AGENT);

    // --- (2) prefetch x(t+1) ---
    const int tn = (t < NT - 1) ? t + 1 : NT - 1;
    const float* xs = X + ((size_t)sm * NT + tn) * ND + sd0;
    f32x4 xr[16];
#pragma unroll
    for (int i = 0; i < 16; ++i) xr[i] = *(const f32x4*)(xs + 4 * i);

    // --- (3) spin-gather h(t) from buffer t&3: data IS the flag ---
    u64 hv16[16];
    {
      u64* src = hg4 + (size_t)(t & 3) * 4096;
#pragma unroll
      for (int i = 0; i < 16; ++i)
        hv16[i] = __hip_atomic_load(src + tid + 256 * i, __ATOMIC_RELAXED, __HIP_MEMORY_SCOPE_AGENT);
      while (true) {
        unsigned int bad = 0;
#pragma unroll
        for (int i = 0; i < 16; ++i) if (hv16[i] == SENT) bad |= (1u << i);
        if (!__any(bad != 0)) break;
#pragma unroll
        for (int i = 0; i < 16; ++i)
          if (bad & (1u << i))
            hv16[i] = __hip_atomic_load(src + tid + 256 * i, __ATOMIC_RELAXED, __HIP_MEMORY_SCOPE_AGENT);
      }
    }
    // drain: gather loads done (values used), reset store acked at LLC, x prefetch done.
    asm volatile("s_waitcnt vmcnt(0)" ::: "memory");

#pragma unroll
    for (int i = 0; i < 16; ++i) {
      const int f = tid + 256 * i;
      *(u64*)&h_lds[(f >> 7) * 520 + (f & 127) * 4] = hv16[i];
    }
    __syncthreads();

    // --- (4) MFMA: gates[32 x 128] = [h | x] . [Whh | Wih]^T slice ---
    f32x4 a00 = {0,0,0,0}, a01 = {0,0,0,0}, a10 = {0,0,0,0}, a11 = {0,0,0,0};
#pragma unroll
    for (int kt = 0; kt < 32; ++kt) {
      const f16* ap = (kt < 16) ? &h_lds[l15 * 520 + kt * 32 + ko]
                                : &x_lds[l15 * 520 + (kt - 16) * 32 + ko];
      f16x8 af0 = *(const f16x8*)ap;
      f16x8 af1 = *(const f16x8*)(ap + 16 * 520);
      a00 = __builtin_amdgcn_mfma_f32_16x16x32_f16(af0, wf[0][kt], a00, 0, 0, 0);
      a01 = __builtin_amdgcn_mfma_f32_16x16x32_f16(af0, wf[1][kt], a01, 0, 0, 0);
      a10 = __builtin_amdgcn_mfma_f32_16x16x32_f16(af1, wf[0][kt], a10, 0, 0, 0);
      a11 = __builtin_amdgcn_mfma_f32_16x16x32_f16(af1, wf[1][kt], a11, 0, 0, 0);
    }

    // --- (5) acc -> g_lds (D frag: col=lane&15, row=(lane>>4)*4+reg) ---
    {
      const int col0 = wv * 32 + l15;
      const int mrow = (lane >> 4) * 4;
#pragma unroll
      for (int r = 0; r < 4; ++r) {
        g_lds[(mrow + r) * 128 + col0]            = a00[r];
        g_lds[(mrow + r) * 128 + col0 + 16]       = a01[r];
        g_lds[(16 + mrow + r) * 128 + col0]       = a10[r];
        g_lds[(16 + mrow + r) * 128 + col0 + 16]  = a11[r];
      }
    }
    __syncthreads();

    // --- (6) elementwise LSTM cell; publish h(t+1) directly (data = flag) ---
    {
      const float* gr = g_lds + em * 128;
      f32x4 vi = *(const f32x4*)(gr + ej0)      ;
      f32x4 vf = *(const f32x4*)(gr + 32 + ej0) ;
      f32x4 vg = *(const f32x4*)(gr + 64 + ej0) ;
      f32x4 vo = *(const f32x4*)(gr + 96 + ej0) ;
      f32x4 bi = *(const f32x4*)(bias_lds + ej0);
      f32x4 bf = *(const f32x4*)(bias_lds + 32 + ej0);
      f32x4 bg = *(const f32x4*)(bias_lds + 64 + ej0);
      f32x4 bo = *(const f32x4*)(bias_lds + 96 + ej0);

      float hv[4];
#pragma unroll
      for (int p = 0; p < 4; ++p) {
        float ig = sigf(vi[p] + bi[p]);
        float fg = sigf(vf[p] + bf[p]);
        float gg = tanhf_(vg[p] + bg[p]);
        float og = sigf(vo[p] + bo[p]);
        float& cc = (p == 0 ? c0 : p == 1 ? c1 : p == 2 ? c2 : c3);
        cc = fg * cc + ig * gg;
        hv[p] = og * tanhf_(cc);
      }
      union { u64 u; f16 h[4]; } pk;
      pk.h[0] = (f16)hv[0]; pk.h[1] = (f16)hv[1]; pk.h[2] = (f16)hv[2]; pk.h[3] = (f16)hv[3];
      __hip_atomic_store(hg4 + (size_t)((t + 1) & 3) * 4096 + myword, pk.u,
                         __ATOMIC_RELAXED, __HIP_MEMORY_SCOPE_AGENT);
      if (t == NT - 1) {
        f32x4 o4; o4[0] = hv[0]; o4[1] = hv[1]; o4[2] = hv[2]; o4[3] = hv[3];
        *(f32x4*)&out[(size_t)em * NH + wgid * WGC + ej0] = o4;
      }
    }

    // --- (7) store prefetched x(t+1) into x_lds (all waves past MFMA reads) ---
#pragma unroll
    for (int i = 0; i < 16; ++i) {
      f16x4 hvv; hvv[0]=(f16)xr[i][0]; hvv[1]=(f16)xr[i][1]; hvv[2]=(f16)xr[i][2]; hvv[3]=(f16)xr[i][3];
      *(f16x4*)&x_lds[sm * 520 + sd0 + 4 * i] = hvv;
    }
    // no trailing barrier: next step's spin-gather is the flow control;
    // LDS hazards are covered by the two __syncthreads inside the step.
  }
}

extern "C" void kernel_launch(void* const* d_in, const int* in_sizes, int n_in,
                              void* d_out, int out_size, void* d_ws, size_t ws_size,
                              hipStream_t stream) {
  const float* X     = (const float*)d_in[0];  // [32][2048][512]
  const float* hprev = (const float*)d_in[1];  // [32][512]
  const float* Wih   = (const float*)d_in[2];  // [2048][512]
  const float* Whh   = (const float*)d_in[3];  // [2048][512]
  const float* bias  = (const float*)d_in[4];  // [2048]
  float* out = (float*)d_out;

  u64* hg4 = (u64*)d_ws;   // 4 * 4096 * 8 = 128 KB

  hipLaunchKernelGGL(lstm_init, dim3(16), dim3(256), 0, stream, hprev, hg4);
  hipLaunchKernelGGL(lstm_rec, dim3(NWG), dim3(256), 0, stream,
                     X, Whh, Wih, bias, out, hg4);
}

// Round 4
// 10042.937 us; speedup vs baseline: 2.2405x; 1.2898x over previous
//
#include <hip/hip_runtime.h>

typedef _Float16 f16;
typedef _Float16 f16x4 __attribute__((ext_vector_type(4)));
typedef _Float16 f16x8 __attribute__((ext_vector_type(8)));
typedef float f32x4 __attribute__((ext_vector_type(4)));
typedef unsigned long long u64;
typedef unsigned short u16;

#define NB 32
#define NT 2048
#define ND 512
#define NH 512
#define NWG 16
#define SENTW 0xFFFFFFFFFFFFFFFFull
#define SENTH ((u16)0xFFFFu)

__device__ __forceinline__ float sigf(float x)  { return 1.0f / (1.0f + __expf(-x)); }
__device__ __forceinline__ float tanhf_(float x){ return 2.0f / (1.0f + __expf(-2.0f * x)) - 1.0f; }

// any halfword of x == 0xFFFF ?
__device__ __forceinline__ bool has_sent(u64 x) {
  u64 a = x & (x >> 8); a &= (a >> 4); a &= (a >> 2); a &= (a >> 1);
  return (a & 0x0001000100010001ull) != 0ull;
}

// fragment-linear LDS index (f16 units) for hg "word" w: m=w>>7, c0=(w&127)*4.
// layout: [kt 16][half 2][lane 64][e 8]; lane = ((c0&31)>>3)*16 + (m&15)
__device__ __forceinline__ int lds_idx(int w) {
  const int m = w >> 7, c0 = (w & 127) << 2;
  const int kt = c0 >> 5, half = m >> 4;
  const int lane16 = (((c0 & 31) >> 3) << 4) + (m & 15);
  return ((kt * 2 + half) * 64 + lane16) * 8 + (c0 & 7);
}

// ---- init: buffer0 = h_prev packed row-major; buffers 1..3 = sentinel ----
__global__ void lstm_init(const float* __restrict__ hprev, u64* __restrict__ hg4) {
  const int g = blockIdx.x * 256 + threadIdx.x;   // 0..4095
  const int m = g >> 7, c0 = (g & 127) << 2;
  const float* s = hprev + m * NH + c0;
  union { u64 u; f16 h[4]; } pk;
  pk.h[0] = (f16)s[0]; pk.h[1] = (f16)s[1]; pk.h[2] = (f16)s[2]; pk.h[3] = (f16)s[3];
  hg4[g] = pk.u;
  hg4[4096 + g] = SENTW;
  hg4[2 * 4096 + g] = SENTW;
  hg4[3 * 4096 + g] = SENTW;
}

// ---- phase 1: xp[t][q][col][b] = (Wih x_t)[q*512+col][b] + bias, f16 ----
// grid (64 tb, 16 cb), 256 threads.
__global__ void __launch_bounds__(256, 1)
lstm_xproj(const float* __restrict__ X, const float* __restrict__ Wih,
           const float* __restrict__ bias, f16* __restrict__ xp) {
  __shared__ f16 x_lds[16384];
  const int tid = threadIdx.x, lane = tid & 63;
  const int wv = tid >> 6, s = wv & 1, bt = wv >> 1;
  const int l15 = lane & 15, ko = (lane >> 4) * 8;
  const int cb = blockIdx.y, tb = blockIdx.x;
  const int colg = cb * 32 + s * 16 + l15;
  const int b0 = bt * 16 + (lane >> 4) * 4;

  f16x8 wf[4][16];
  float bs[4];
#pragma unroll
  for (int q = 0; q < 4; ++q) {
    const size_t grow = (size_t)(q * NH + colg);
    bs[q] = bias[grow];
#pragma unroll
    for (int kt = 0; kt < 16; ++kt) {
      const float* src = Wih + grow * ND + kt * 32 + ko;
      f32x4 u0 = *(const f32x4*)src, u1 = *(const f32x4*)(src + 4);
      f16x8 w;
      w[0]=(f16)u0[0]; w[1]=(f16)u0[1]; w[2]=(f16)u0[2]; w[3]=(f16)u0[3];
      w[4]=(f16)u1[0]; w[5]=(f16)u1[1]; w[6]=(f16)u1[2]; w[7]=(f16)u1[3];
      wf[q][kt] = w;
    }
  }

  for (int tt = 0; tt < 32; ++tt) {
    const int t = tb * 32 + tt;
    // stage x(t) into fragment-linear LDS
#pragma unroll
    for (int i = 0; i < 16; ++i) {
      const int w = tid + 256 * i;
      const int m = w >> 7, c0 = (w & 127) << 2;
      f32x4 v = *(const f32x4*)(X + ((size_t)m * NT + t) * ND + c0);
      union { u64 u; f16 h[4]; } pk;
      pk.h[0]=(f16)v[0]; pk.h[1]=(f16)v[1]; pk.h[2]=(f16)v[2]; pk.h[3]=(f16)v[3];
      *(u64*)&x_lds[lds_idx(w)] = pk.u;
    }
    __syncthreads();

    f32x4 acc[4] = {{0,0,0,0},{0,0,0,0},{0,0,0,0},{0,0,0,0}};
#pragma unroll
    for (int kt = 0; kt < 16; ++kt) {
      f16x8 af = *(const f16x8*)&x_lds[((kt * 2 + bt) * 64 + lane) * 8];
      acc[0] = __builtin_amdgcn_mfma_f32_16x16x32_f16(af, wf[0][kt], acc[0], 0, 0, 0);
      acc[1] = __builtin_amdgcn_mfma_f32_16x16x32_f16(af, wf[1][kt], acc[1], 0, 0, 0);
      acc[2] = __builtin_amdgcn_mfma_f32_16x16x32_f16(af, wf[2][kt], acc[2], 0, 0, 0);
      acc[3] = __builtin_amdgcn_mfma_f32_16x16x32_f16(af, wf[3][kt], acc[3], 0, 0, 0);
    }
#pragma unroll
    for (int q = 0; q < 4; ++q) {
      f16x4 o;
      o[0]=(f16)(acc[q][0]+bs[q]); o[1]=(f16)(acc[q][1]+bs[q]);
      o[2]=(f16)(acc[q][2]+bs[q]); o[3]=(f16)(acc[q][3]+bs[q]);
      *(f16x4*)&xp[((((size_t)t * 4 + q) * 512) + colg) * 32 + b0] = o;
    }
    __syncthreads();
  }
}

// ---- persistent recurrent kernel: 16 WGs x 256 threads ----
__global__ void __launch_bounds__(256, 1)
lstm_rec(const float* __restrict__ Whh,   // [4H][H] f32
         const f16*   __restrict__ xp,    // [T][4][512][32] f16
         float* __restrict__ out,         // [B][H]
         u64* __restrict__ hg4) {         // [4][4096] u64 (f16 pieces)
  __shared__ f16 h_lin[2][16384];

  const int tid  = threadIdx.x;
  const int wgid = blockIdx.x;
  const int lane = tid & 63;
  const int wv   = tid >> 6, s = wv & 1, bt = wv >> 1;
  const int l15  = lane & 15, ko = (lane >> 4) * 8;
  const int colg = wgid * 32 + s * 16 + l15;  // h / gate column
  const int b0   = bt * 16 + (lane >> 4) * 4; // first of 4 batch rows

  // Whh B-frags: wf[q][kt], q = gate type
  f16x8 wf[4][16];
#pragma unroll
  for (int q = 0; q < 4; ++q) {
    const size_t grow = (size_t)(q * NH + colg);
#pragma unroll
    for (int kt = 0; kt < 16; ++kt) {
      const float* src = Whh + grow * NH + kt * 32 + ko;
      f32x4 u0 = *(const f32x4*)src, u1 = *(const f32x4*)(src + 4);
      f16x8 w;
      w[0]=(f16)u0[0]; w[1]=(f16)u0[1]; w[2]=(f16)u0[2]; w[3]=(f16)u0[3];
      w[4]=(f16)u1[0]; w[5]=(f16)u1[1]; w[6]=(f16)u1[2]; w[7]=(f16)u1[3];
      wf[q][kt] = w;
    }
  }

  u16* hgh = (u16*)hg4;   // halfword view: buffer b at b*16384

  // preload xp(t=0)
  f16x4 xpv[4];
#pragma unroll
  for (int q = 0; q < 4; ++q)
    xpv[q] = *(const f16x4*)&xp[(((size_t)0 * 4 + q) * 512 + colg) * 32 + b0];

  float c[4] = {0.f, 0.f, 0.f, 0.f};

  for (int t = 0; t < NT; ++t) {
    // (1) reset my 4 pieces of buffer (t+2)&3 (drained by vmcnt before publish)
    {
      u16* rb = hgh + (size_t)((t + 2) & 3) * 16384;
#pragma unroll
      for (int r = 0; r < 4; ++r)
        __hip_atomic_store(rb + (b0 + r) * 512 + colg, SENTH,
                           __ATOMIC_RELAXED, __HIP_MEMORY_SCOPE_AGENT);
    }
    // (2) prefetch xp(t+1)
    const int tn = (t < NT - 1) ? t + 1 : NT - 1;
    f16x4 xpn[4];
#pragma unroll
    for (int q = 0; q < 4; ++q)
      xpn[q] = *(const f16x4*)&xp[(((size_t)tn * 4 + q) * 512 + colg) * 32 + b0];

    // (3) spin-gather h(t) from buffer t&3 (per-halfword sentinel check)
    u64 hv16[16];
    {
      u64* src = hg4 + (size_t)(t & 3) * 4096;
#pragma unroll
      for (int i = 0; i < 16; ++i)
        hv16[i] = __hip_atomic_load(src + tid + 256 * i, __ATOMIC_RELAXED, __HIP_MEMORY_SCOPE_AGENT);
      while (true) {
        unsigned int bad = 0;
#pragma unroll
        for (int i = 0; i < 16; ++i) if (has_sent(hv16[i])) bad |= (1u << i);
        if (!__any(bad != 0)) break;
#pragma unroll
        for (int i = 0; i < 16; ++i)
          if (bad & (1u << i))
            hv16[i] = __hip_atomic_load(src + tid + 256 * i, __ATOMIC_RELAXED, __HIP_MEMORY_SCOPE_AGENT);
      }
    }
    // drain: reset stores + xp prefetch + gather loads all complete
    asm volatile("s_waitcnt vmcnt(0)" ::: "memory");

    // (4) scatter to fragment-linear LDS (conflict-free b64 writes)
    f16* hb = h_lin[t & 1];
#pragma unroll
    for (int i = 0; i < 16; ++i)
      *(u64*)&hb[lds_idx(tid + 256 * i)] = hv16[i];
    __syncthreads();

    // (5) MFMA: acc[q] = h(t) . Whh_q^T  (linear ds_read_b128, zero conflicts)
    f32x4 acc[4] = {{0,0,0,0},{0,0,0,0},{0,0,0,0},{0,0,0,0}};
#pragma unroll
    for (int kt = 0; kt < 16; ++kt) {
      f16x8 af = *(const f16x8*)&hb[((kt * 2 + bt) * 64 + lane) * 8];
      acc[0] = __builtin_amdgcn_mfma_f32_16x16x32_f16(af, wf[0][kt], acc[0], 0, 0, 0);
      acc[1] = __builtin_amdgcn_mfma_f32_16x16x32_f16(af, wf[1][kt], acc[1], 0, 0, 0);
      acc[2] = __builtin_amdgcn_mfma_f32_16x16x32_f16(af, wf[2][kt], acc[2], 0, 0, 0);
      acc[3] = __builtin_amdgcn_mfma_f32_16x16x32_f16(af, wf[3][kt], acc[3], 0, 0, 0);
    }

    // (6) in-register LSTM cell for 4 (batch b0+r, col colg) elements
    {
      u16* pb = hgh + (size_t)((t + 1) & 3) * 16384;
#pragma unroll
      for (int r = 0; r < 3 + 1; ++r) {
        float gi = acc[0][r] + (float)xpv[0][r];
        float gf = acc[1][r] + (float)xpv[1][r];
        float gg = acc[2][r] + (float)xpv[2][r];
        float go = acc[3][r] + (float)xpv[3][r];
        c[r] = sigf(gf) * c[r] + sigf(gi) * tanhf_(gg);
        float hv = sigf(go) * tanhf_(c[r]);
        union { f16 h; u16 u; } cv; cv.h = (f16)hv;
        __hip_atomic_store(pb + (b0 + r) * 512 + colg, cv.u,
                           __ATOMIC_RELAXED, __HIP_MEMORY_SCOPE_AGENT);
        if (t == NT - 1) out[(size_t)(b0 + r) * NH + colg] = hv;
      }
    }
    // roll xp prefetch
#pragma unroll
    for (int q = 0; q < 4; ++q) xpv[q] = xpn[q];
    // no trailing barrier: next step writes the other h_lin buffer; the
    // per-step __syncthreads orders buffer reuse at distance 2.
  }
}

extern "C" void kernel_launch(void* const* d_in, const int* in_sizes, int n_in,
                              void* d_out, int out_size, void* d_ws, size_t ws_size,
                              hipStream_t stream) {
  const float* X     = (const float*)d_in[0];  // [32][2048][512]
  const float* hprev = (const float*)d_in[1];  // [32][512]
  const float* Wih   = (const float*)d_in[2];  // [2048][512]
  const float* Whh   = (const float*)d_in[3];  // [2048][512]
  const float* bias  = (const float*)d_in[4];  // [2048]
  float* out = (float*)d_out;

  u64* hg4 = (u64*)d_ws;                              // 128 KB
  f16* xp  = (f16*)((char*)d_ws + (size_t)(1 << 17)); // 2048*4*512*32*2B = 256 MB

  hipLaunchKernelGGL(lstm_init, dim3(16), dim3(256), 0, stream, hprev, hg4);
  hipLaunchKernelGGL(lstm_xproj, dim3(64, 16), dim3(256), 0, stream, X, Wih, bias, xp);
  hipLaunchKernelGGL(lstm_rec, dim3(NWG), dim3(256), 0, stream, Whh, xp, out, hg4);
}